// Round 2
// baseline (510.317 us; speedup 1.0000x reference)
//
#include <hip/hip_runtime.h>

// GCNConv: out[v] = isd[v] * sum_{(u->v)} x[u] * isd[u],  isd = rsqrt(max(outdeg,1))
// N=100000, E=1600000, D=128 fp32.
//
// R1 -> R2: bucketed gather killed the 800MB atomic write storm (866 -> 367us).
// R2 -> R3: dst-range slicing for bucket-store L2 locality (367 -> 343us).
// R3 -> R4 FAILED: workgroup-scope atomics did NOT stay in per-XCD L2
//           (WRITE_SIZE 134->127MB, build 130->164us). Learned: every global
//           atomic RMW = ~32B coherence-point transaction regardless of scope;
//           atomic op throughput (~25G/s) is the wall.
// R4 -> R5: eliminate the 3.2M global atomics entirely. Atomic-free build:
//           (1) hist: per-(axis,slice,chunk) LDS histograms -> scratch, plain
//               stores only;
//           (2) scan: per-node chunk-prefix (exclusive) for dst axis + deg
//               totals for src axis (isd fused here);
//           (3) scatter: LDS counters seeded with chunk-prefix give globally
//               unique bucket slots via LDS atomics; plain global stores.
//           Only remaining device atomics: rare bucket overflow (>CAP).

#define D_FEAT 128
#define CAP 32
#define NODES_PER_BLOCK 8   // gather: 256 threads, 32 lanes (float4) per node
#define SLICE_NODES 12500   // LDS histogram bins per block (50KB)
#define SLICE_MAX  12512
#define NCHUNKS 16

// ---- R5 atomic-free build pipeline ----

__global__ void hist_kernel(const int* __restrict__ src, const int* __restrict__ dst,
                            int* __restrict__ H, int E, int N,
                            int nslices, int sliceSz, int chunkSz) {
    int bid = blockIdx.x;
    int c  = bid % NCHUNKS;
    int s  = (bid / NCHUNKS) % nslices;
    int ax = bid / (NCHUNKS * nslices);          // 0 = src (deg), 1 = dst (cnt)
    const int* __restrict__ arr = ax ? dst : src;

    __shared__ int h[SLICE_MAX];
    int lo = s * sliceSz;
    int hi = min(N, lo + sliceSz);
    int span = hi - lo;
    for (int i = threadIdx.x; i < span; i += blockDim.x) h[i] = 0;
    __syncthreads();

    int beg = c * chunkSz;
    int end = min(E, beg + chunkSz);
    // int4 main loop (beg and chunkSz are multiples of 4)
    int i = beg + (int)threadIdx.x * 4;
    for (; i + 3 < end; i += blockDim.x * 4) {
        int4 v = *reinterpret_cast<const int4*>(&arr[i]);
        unsigned o;
        o = (unsigned)(v.x - lo); if (o < (unsigned)span) atomicAdd(&h[o], 1);
        o = (unsigned)(v.y - lo); if (o < (unsigned)span) atomicAdd(&h[o], 1);
        o = (unsigned)(v.z - lo); if (o < (unsigned)span) atomicAdd(&h[o], 1);
        o = (unsigned)(v.w - lo); if (o < (unsigned)span) atomicAdd(&h[o], 1);
    }
    if (i < end) {                               // <=1 thread lands here; <=3 elems
        for (int k = i; k < end; ++k) {
            unsigned o = (unsigned)(arr[k] - lo);
            if (o < (unsigned)span) atomicAdd(&h[o], 1);
        }
    }
    __syncthreads();

    size_t base = ((size_t)(ax * nslices + s) * NCHUNKS + c) * (size_t)sliceSz;
    for (int j = threadIdx.x; j < span; j += blockDim.x) H[base + j] = h[j];
}

__global__ void scan_kernel(int* __restrict__ H, float* __restrict__ isd,
                            int* __restrict__ cnt, int N,
                            int nslices, int sliceSz) {
    int g = blockIdx.x * blockDim.x + threadIdx.x;   // over nslices*sliceSz
    int s = g / sliceSz;
    int i = g - s * sliceSz;
    if (s >= nslices) return;
    int node = s * sliceSz + i;
    if (node >= N) return;

    // src axis: total out-degree -> isd
    size_t baseS = ((size_t)(0 * nslices + s) * NCHUNKS) * (size_t)sliceSz + i;
    int deg = 0;
    for (int c = 0; c < NCHUNKS; ++c) deg += H[baseS + (size_t)c * sliceSz];
    isd[node] = rsqrtf(fmaxf((float)deg, 1.0f));

    // dst axis: exclusive prefix over chunks (in place) + total
    size_t baseD = ((size_t)(1 * nslices + s) * NCHUNKS) * (size_t)sliceSz + i;
    int run = 0;
    for (int c = 0; c < NCHUNKS; ++c) {
        size_t idx = baseD + (size_t)c * sliceSz;
        int t = H[idx];
        H[idx] = run;
        run += t;
    }
    cnt[node] = run;
}

__global__ void scatter_kernel(const int* __restrict__ src, const int* __restrict__ dst,
                               const int* __restrict__ H,   // dst-axis chunk prefixes
                               int* __restrict__ bucket, int2* __restrict__ ovf,
                               int* __restrict__ novf, int E, int N,
                               int nslices, int sliceSz, int chunkSz) {
    int bid = blockIdx.x;
    int c = bid % NCHUNKS;
    int s = bid / NCHUNKS;

    __shared__ int lc[SLICE_MAX];
    int lo = s * sliceSz;
    int hi = min(N, lo + sliceSz);
    int span = hi - lo;
    size_t base = ((size_t)(nslices + s) * NCHUNKS + c) * (size_t)sliceSz;
    for (int i = threadIdx.x; i < span; i += blockDim.x) lc[i] = H[base + i];
    __syncthreads();

    int beg = c * chunkSz;
    int end = min(E, beg + chunkSz);
    for (int i = beg + (int)threadIdx.x; i < end; i += blockDim.x) {
        int d  = dst[i];
        int sv = src[i];                          // unconditional: coalesced
        unsigned o = (unsigned)(d - lo);
        if (o < (unsigned)span) {
            int slot = atomicAdd(&lc[o], 1);      // LDS atomic: globally-unique slot
            if (slot < CAP) {
                bucket[d * CAP + slot] = sv;      // plain store
            } else {
                int ov = atomicAdd(novf, 1);      // rare Poisson(16) tail
                ovf[ov] = make_int2(sv, d);
            }
        }
    }
}

// 8 nodes per 256-thread block; 32 threads per node, float4 per thread.
__global__ void gather_kernel(const float4* __restrict__ x4,
                              const int* __restrict__ cnt,
                              const int* __restrict__ bucket,
                              const float* __restrict__ isd,
                              float4* __restrict__ out4, int N) {
    __shared__ int   sh_idx[NODES_PER_BLOCK * CAP];
    __shared__ float sh_w[NODES_PER_BLOCK * CAP];
    int t = threadIdx.x;
    int node_slot = t >> 5;
    int lane = t & 31;
    int d = blockIdx.x * NODES_PER_BLOCK + node_slot;

    int c = 0;
    if (d < N) {
        c = min(cnt[d], CAP);
        if (lane < c) {
            int s = bucket[d * CAP + lane];
            sh_idx[node_slot * CAP + lane] = s;
            sh_w[node_slot * CAP + lane] = isd[s];
        }
    }
    __syncthreads();
    if (d >= N) return;

    float4 acc = {0.f, 0.f, 0.f, 0.f};
    #pragma unroll 4
    for (int k = 0; k < c; ++k) {
        int s   = sh_idx[node_slot * CAP + k];   // broadcast LDS read
        float w = sh_w[node_slot * CAP + k];
        float4 v = x4[s * 32 + lane];            // 512B coalesced row gather
        acc.x += v.x * w; acc.y += v.y * w;
        acc.z += v.z * w; acc.w += v.w * w;
    }
    float wd = isd[d];
    acc.x *= wd; acc.y *= wd; acc.z *= wd; acc.w *= wd;
    out4[d * 32 + lane] = acc;                   // single non-atomic row write
}

__global__ void overflow_kernel(const float* __restrict__ x,
                                const float* __restrict__ isd,
                                const int2* __restrict__ ovf,
                                const int* __restrict__ novf,
                                float* __restrict__ out) {
    int n = *novf;
    for (int e = blockIdx.x; e < n; e += gridDim.x) {
        int2 sd = ovf[e];
        float coef = isd[sd.x] * isd[sd.y];
        atomicAdd(&out[sd.y * D_FEAT + threadIdx.x],
                  x[sd.x * D_FEAT + threadIdx.x] * coef);
    }
}

// ---- tier-2 (ws too small for scratch): R3 atomic build ----
#define NSLICES_T2 8
#define BPS 512

__global__ void build_kernel(const int* __restrict__ src, const int* __restrict__ dst,
                             int* __restrict__ deg, int* __restrict__ cnt,
                             int* __restrict__ bucket, int2* __restrict__ ovf,
                             int* __restrict__ novf, int E, int sliceSz) {
    int slice = blockIdx.x & (NSLICES_T2 - 1);
    int chunk = blockIdx.x >> 3;
    int lo = slice * sliceSz;
    int hi = lo + sliceSz;
    int chunkSz = (E + BPS - 1) / BPS;
    int beg = chunk * chunkSz;
    int end = min(E, beg + chunkSz);

    for (int i = beg + (int)threadIdx.x; i < end; i += blockDim.x) {
        int s = src[i];
        int d = dst[i];
        if (d >= lo && d < hi) {
            int slot = atomicAdd(&cnt[d], 1);
            if (slot < CAP) {
                bucket[d * CAP + slot] = s;
            } else {
                int o = atomicAdd(novf, 1);
                ovf[o] = make_int2(s, d);
            }
        }
        if (s >= lo && s < hi) {
            atomicAdd(&deg[s], 1);
        }
    }
}

__global__ void isd_kernel(const int* __restrict__ deg, float* __restrict__ isd, int N) {
    int i = blockIdx.x * blockDim.x + threadIdx.x;
    if (i < N) isd[i] = rsqrtf(fmaxf((float)deg[i], 1.0f));
}

// ---- tier-3 fallback (ws tiny): round-1 atomic scatter ----
__global__ void fb_degree_kernel(const int* __restrict__ src,
                                 float* __restrict__ deg, int E) {
    int i = blockIdx.x * blockDim.x + threadIdx.x;
    if (i < E) atomicAdd(&deg[src[i]], 1.0f);
}
__global__ void fb_inv_sqrt_kernel(float* __restrict__ deg, int N) {
    int i = blockIdx.x * blockDim.x + threadIdx.x;
    if (i < N) deg[i] = rsqrtf(fmaxf(deg[i], 1.0f));
}
__global__ void fb_scatter_kernel(const float* __restrict__ x,
                                  const int* __restrict__ src,
                                  const int* __restrict__ dst,
                                  const float* __restrict__ isd,
                                  float* __restrict__ out, int E) {
    int e = blockIdx.x;
    if (e >= E) return;
    int f = threadIdx.x;
    int s = src[e], d = dst[e];
    float coef = isd[s] * isd[d];
    atomicAdd(&out[(long)d * D_FEAT + f], x[(long)s * D_FEAT + f] * coef);
}

extern "C" void kernel_launch(void* const* d_in, const int* in_sizes, int n_in,
                              void* d_out, int out_size, void* d_ws, size_t ws_size,
                              hipStream_t stream) {
    const float* x   = (const float*)d_in[0];
    const int*   src = (const int*)d_in[1];
    const int*   dst = (const int*)d_in[2];
    float* out = (float*)d_out;

    int N = in_sizes[0] / D_FEAT;   // 100000
    int E = in_sizes[1];            // 1600000

    int nslices = (N + SLICE_NODES - 1) / SLICE_NODES;   // 8 for N=100000
    int sliceSz = SLICE_NODES;
    int chunkSz = (((E + NCHUNKS - 1) / NCHUNKS) + 3) & ~3; // 4-aligned

    size_t hSz = (size_t)2 * nslices * NCHUNKS * sliceSz * 4;

    size_t off_cnt    = 0;
    size_t off_isd    = off_cnt + (size_t)N * 4;
    size_t off_misc   = off_isd + (size_t)N * 4;   // novf @+0
    size_t off_bucket = off_misc + 64;
    size_t off_H      = off_bucket + (size_t)N * CAP * 4;
    size_t off_ovf    = off_H + hSz;
    size_t needed     = off_ovf + (size_t)E * 8;

    if (ws_size >= needed) {
        char* ws = (char*)d_ws;
        int*   cnt    = (int*)(ws + off_cnt);
        float* isd    = (float*)(ws + off_isd);
        int*   novf   = (int*)(ws + off_misc);
        int*   bucket = (int*)(ws + off_bucket);
        int*   H      = (int*)(ws + off_H);
        int2*  ovf    = (int2*)(ws + off_ovf);

        hipMemsetAsync(novf, 0, 16, stream);

        hist_kernel<<<2 * nslices * NCHUNKS, 256, 0, stream>>>(
            src, dst, H, E, N, nslices, sliceSz, chunkSz);
        scan_kernel<<<(nslices * sliceSz + 255) / 256, 256, 0, stream>>>(
            H, isd, cnt, N, nslices, sliceSz);
        scatter_kernel<<<nslices * NCHUNKS, 256, 0, stream>>>(
            src, dst, H, bucket, ovf, novf, E, N, nslices, sliceSz, chunkSz);
        gather_kernel<<<(N + NODES_PER_BLOCK - 1) / NODES_PER_BLOCK, 256, 0, stream>>>(
            (const float4*)x, cnt, bucket, isd, (float4*)out, N);
        overflow_kernel<<<64, D_FEAT, 0, stream>>>(x, isd, ovf, novf, out);
        return;
    }

    // tier-2: R3 atomic build (needs ~26.8MB)
    size_t t2_deg    = 0;
    size_t t2_cnt    = t2_deg + (size_t)N * 4;
    size_t t2_isd    = t2_cnt + (size_t)N * 4;
    size_t t2_novf   = t2_isd + (size_t)N * 4;
    size_t t2_bucket = t2_novf + 16;
    size_t t2_ovf    = t2_bucket + (size_t)N * CAP * 4;
    size_t t2_needed = t2_ovf + (size_t)E * 8;

    if (ws_size >= t2_needed) {
        char* ws = (char*)d_ws;
        int*   deg    = (int*)(ws + t2_deg);
        int*   cnt    = (int*)(ws + t2_cnt);
        float* isd    = (float*)(ws + t2_isd);
        int*   novf   = (int*)(ws + t2_novf);
        int*   bucket = (int*)(ws + t2_bucket);
        int2*  ovf    = (int2*)(ws + t2_ovf);

        hipMemsetAsync(ws, 0, t2_novf + 16, stream);
        int sl = (N + NSLICES_T2 - 1) / NSLICES_T2;
        build_kernel<<<NSLICES_T2 * BPS, 256, 0, stream>>>(src, dst, deg, cnt,
                                                           bucket, ovf, novf, E, sl);
        isd_kernel<<<(N + 255) / 256, 256, 0, stream>>>(deg, isd, N);
        gather_kernel<<<(N + NODES_PER_BLOCK - 1) / NODES_PER_BLOCK, 256, 0, stream>>>(
            (const float4*)x, cnt, bucket, isd, (float4*)out, N);
        overflow_kernel<<<64, D_FEAT, 0, stream>>>(x, isd, ovf, novf, out);
        return;
    }

    // tier-3 naive
    float* deg = (float*)d_ws;
    hipMemsetAsync(deg, 0, (size_t)N * sizeof(float), stream);
    hipMemsetAsync(out, 0, (size_t)out_size * sizeof(float), stream);
    fb_degree_kernel<<<(E + 255) / 256, 256, 0, stream>>>(src, deg, E);
    fb_inv_sqrt_kernel<<<(N + 255) / 256, 256, 0, stream>>>(deg, N);
    fb_scatter_kernel<<<E, D_FEAT, 0, stream>>>(x, src, dst, deg, out, E);
}

// Round 3
// 317.208 us; speedup vs baseline: 1.6088x; 1.6088x over previous
//
#include <hip/hip_runtime.h>

// GCNConv: out[v] = isd[v] * sum_{(u->v)} x[u] * isd[u],  isd = rsqrt(max(outdeg,1))
// N=100000, E=1600000, D=128 fp32.
//
// R1 -> R2: bucketed gather killed the 800MB atomic write storm (866 -> 367us).
// R2 -> R3: dst-range slicing for bucket-store L2 locality (367 -> 343us).
// R3 -> R4 FAILED: scope-relaxed atomics don't stay in per-XCD L2; atomic op
//           throughput (~25G/s) is the wall regardless of scope.
// R4 -> R5: atomic-free build (LDS hist -> chunk prefix -> LDS-seeded scatter).
//           Structure works (no atomic storm) but 510us total: scatter had a
//           128-block grid (5.8% occupancy), hist 256 blocks. Parallelism bug.
// R5 -> R6: chunk dim 16 -> 64 (runtime-fit): scatter 512 blocks, hist 1024.
//           H scratch in ushort (clamped; clamp-affected slots are >=CAP so
//           they route to ovf -- uniqueness preserved). int4 edge loads in
//           scatter. Total edge-scan traffic unchanged (LLC-absorbed).

#define D_FEAT 128
#define CAP 32
#define NODES_PER_BLOCK 8   // gather: 256 threads, 32 lanes (float4) per node
#define SLICE_NODES 12500   // LDS histogram bins per block (50KB)
#define SLICE_MAX  12512

// ---- atomic-free build pipeline ----

__global__ void hist_kernel(const int* __restrict__ src, const int* __restrict__ dst,
                            unsigned short* __restrict__ H, int E, int N,
                            int nslices, int sliceSz, int chunkSz, int nc) {
    int bid = blockIdx.x;
    int c  = bid % nc;
    int s  = (bid / nc) % nslices;
    int ax = bid / (nc * nslices);               // 0 = src (deg), 1 = dst (cnt)
    const int* __restrict__ arr = ax ? dst : src;

    __shared__ int h[SLICE_MAX];
    int lo = s * sliceSz;
    int hi = min(N, lo + sliceSz);
    int span = hi - lo;
    for (int i = threadIdx.x; i < span; i += blockDim.x) h[i] = 0;
    __syncthreads();

    int beg = c * chunkSz;
    int end = min(E, beg + chunkSz);
    int i = beg + (int)threadIdx.x * 4;
    for (; i + 3 < end; i += blockDim.x * 4) {
        int4 v = *reinterpret_cast<const int4*>(&arr[i]);
        unsigned o;
        o = (unsigned)(v.x - lo); if (o < (unsigned)span) atomicAdd(&h[o], 1);
        o = (unsigned)(v.y - lo); if (o < (unsigned)span) atomicAdd(&h[o], 1);
        o = (unsigned)(v.z - lo); if (o < (unsigned)span) atomicAdd(&h[o], 1);
        o = (unsigned)(v.w - lo); if (o < (unsigned)span) atomicAdd(&h[o], 1);
    }
    if (i < end) {                               // <=1 thread; <=3 elems
        for (int k = i; k < end; ++k) {
            unsigned o = (unsigned)(arr[k] - lo);
            if (o < (unsigned)span) atomicAdd(&h[o], 1);
        }
    }
    __syncthreads();

    size_t base = ((size_t)(ax * nslices + s) * nc + c) * (size_t)sliceSz;
    for (int j = threadIdx.x; j < span; j += blockDim.x)
        H[base + j] = (unsigned short)min(h[j], 65535);
}

__global__ void scan_kernel(unsigned short* __restrict__ H, float* __restrict__ isd,
                            int* __restrict__ cnt, int N,
                            int nslices, int sliceSz, int nc) {
    int g = blockIdx.x * blockDim.x + threadIdx.x;   // over nslices*sliceSz
    int s = g / sliceSz;
    int i = g - s * sliceSz;
    if (s >= nslices) return;
    int node = s * sliceSz + i;
    if (node >= N) return;

    // src axis: total out-degree -> isd (fused)
    size_t baseS = ((size_t)(0 * nslices + s) * nc) * (size_t)sliceSz + i;
    int deg = 0;
    for (int c = 0; c < nc; ++c) deg += H[baseS + (size_t)c * sliceSz];
    isd[node] = rsqrtf(fmaxf((float)deg, 1.0f));

    // dst axis: exclusive prefix over chunks (in place, clamped) + total
    size_t baseD = ((size_t)(1 * nslices + s) * nc) * (size_t)sliceSz + i;
    int run = 0;
    for (int c = 0; c < nc; ++c) {
        size_t idx = baseD + (size_t)c * sliceSz;
        int t = H[idx];
        H[idx] = (unsigned short)min(run, 65535);  // clamped seeds are >=CAP -> ovf
        run += t;
    }
    cnt[node] = run;
}

__global__ void scatter_kernel(const int* __restrict__ src, const int* __restrict__ dst,
                               const unsigned short* __restrict__ H, // dst chunk prefixes
                               int* __restrict__ bucket, int2* __restrict__ ovf,
                               int* __restrict__ novf, int E, int N,
                               int nslices, int sliceSz, int chunkSz, int nc) {
    int bid = blockIdx.x;
    int c = bid % nc;
    int s = bid / nc;

    __shared__ int lc[SLICE_MAX];
    int lo = s * sliceSz;
    int hi = min(N, lo + sliceSz);
    int span = hi - lo;
    size_t base = ((size_t)(nslices + s) * nc + c) * (size_t)sliceSz;
    for (int i = threadIdx.x; i < span; i += blockDim.x) lc[i] = H[base + i];
    __syncthreads();

    int beg = c * chunkSz;
    int end = min(E, beg + chunkSz);
    int i = beg + (int)threadIdx.x * 4;
    for (; i + 3 < end; i += blockDim.x * 4) {
        int4 dv = *reinterpret_cast<const int4*>(&dst[i]);
        int4 sv = *reinterpret_cast<const int4*>(&src[i]);
        #pragma unroll
        for (int k = 0; k < 4; ++k) {
            int d  = (&dv.x)[k];
            int sx = (&sv.x)[k];
            unsigned o = (unsigned)(d - lo);
            if (o < (unsigned)span) {
                int slot = atomicAdd(&lc[o], 1);      // LDS atomic: unique slot
                if (slot < CAP) {
                    bucket[d * CAP + slot] = sx;      // plain store
                } else {
                    int ov = atomicAdd(novf, 1);      // rare tail
                    ovf[ov] = make_int2(sx, d);
                }
            }
        }
    }
    if (i < end) {                               // <=1 thread; <=3 elems
        for (int k = i; k < end; ++k) {
            int d  = dst[k];
            int sx = src[k];
            unsigned o = (unsigned)(d - lo);
            if (o < (unsigned)span) {
                int slot = atomicAdd(&lc[o], 1);
                if (slot < CAP) {
                    bucket[d * CAP + slot] = sx;
                } else {
                    int ov = atomicAdd(novf, 1);
                    ovf[ov] = make_int2(sx, d);
                }
            }
        }
    }
}

// 8 nodes per 256-thread block; 32 threads per node, float4 per thread.
__global__ void gather_kernel(const float4* __restrict__ x4,
                              const int* __restrict__ cnt,
                              const int* __restrict__ bucket,
                              const float* __restrict__ isd,
                              float4* __restrict__ out4, int N) {
    __shared__ int   sh_idx[NODES_PER_BLOCK * CAP];
    __shared__ float sh_w[NODES_PER_BLOCK * CAP];
    int t = threadIdx.x;
    int node_slot = t >> 5;
    int lane = t & 31;
    int d = blockIdx.x * NODES_PER_BLOCK + node_slot;

    int c = 0;
    if (d < N) {
        c = min(cnt[d], CAP);
        if (lane < c) {
            int s = bucket[d * CAP + lane];
            sh_idx[node_slot * CAP + lane] = s;
            sh_w[node_slot * CAP + lane] = isd[s];
        }
    }
    __syncthreads();
    if (d >= N) return;

    float4 acc = {0.f, 0.f, 0.f, 0.f};
    #pragma unroll 4
    for (int k = 0; k < c; ++k) {
        int s   = sh_idx[node_slot * CAP + k];   // broadcast LDS read
        float w = sh_w[node_slot * CAP + k];
        float4 v = x4[s * 32 + lane];            // 512B coalesced row gather
        acc.x += v.x * w; acc.y += v.y * w;
        acc.z += v.z * w; acc.w += v.w * w;
    }
    float wd = isd[d];
    acc.x *= wd; acc.y *= wd; acc.z *= wd; acc.w *= wd;
    out4[d * 32 + lane] = acc;                   // single non-atomic row write
}

__global__ void overflow_kernel(const float* __restrict__ x,
                                const float* __restrict__ isd,
                                const int2* __restrict__ ovf,
                                const int* __restrict__ novf,
                                float* __restrict__ out) {
    int n = *novf;
    for (int e = blockIdx.x; e < n; e += gridDim.x) {
        int2 sd = ovf[e];
        float coef = isd[sd.x] * isd[sd.y];
        atomicAdd(&out[sd.y * D_FEAT + threadIdx.x],
                  x[sd.x * D_FEAT + threadIdx.x] * coef);
    }
}

// ---- tier-2 (ws too small for scratch): R3 atomic build ----
#define NSLICES_T2 8
#define BPS 512

__global__ void build_kernel(const int* __restrict__ src, const int* __restrict__ dst,
                             int* __restrict__ deg, int* __restrict__ cnt,
                             int* __restrict__ bucket, int2* __restrict__ ovf,
                             int* __restrict__ novf, int E, int sliceSz) {
    int slice = blockIdx.x & (NSLICES_T2 - 1);
    int chunk = blockIdx.x >> 3;
    int lo = slice * sliceSz;
    int hi = lo + sliceSz;
    int chunkSz = (E + BPS - 1) / BPS;
    int beg = chunk * chunkSz;
    int end = min(E, beg + chunkSz);

    for (int i = beg + (int)threadIdx.x; i < end; i += blockDim.x) {
        int s = src[i];
        int d = dst[i];
        if (d >= lo && d < hi) {
            int slot = atomicAdd(&cnt[d], 1);
            if (slot < CAP) {
                bucket[d * CAP + slot] = s;
            } else {
                int o = atomicAdd(novf, 1);
                ovf[o] = make_int2(s, d);
            }
        }
        if (s >= lo && s < hi) {
            atomicAdd(&deg[s], 1);
        }
    }
}

__global__ void isd_kernel(const int* __restrict__ deg, float* __restrict__ isd, int N) {
    int i = blockIdx.x * blockDim.x + threadIdx.x;
    if (i < N) isd[i] = rsqrtf(fmaxf((float)deg[i], 1.0f));
}

// ---- tier-3 fallback (ws tiny): round-1 atomic scatter ----
__global__ void fb_degree_kernel(const int* __restrict__ src,
                                 float* __restrict__ deg, int E) {
    int i = blockIdx.x * blockDim.x + threadIdx.x;
    if (i < E) atomicAdd(&deg[src[i]], 1.0f);
}
__global__ void fb_inv_sqrt_kernel(float* __restrict__ deg, int N) {
    int i = blockIdx.x * blockDim.x + threadIdx.x;
    if (i < N) deg[i] = rsqrtf(fmaxf(deg[i], 1.0f));
}
__global__ void fb_scatter_kernel(const float* __restrict__ x,
                                  const int* __restrict__ src,
                                  const int* __restrict__ dst,
                                  const float* __restrict__ isd,
                                  float* __restrict__ out, int E) {
    int e = blockIdx.x;
    if (e >= E) return;
    int f = threadIdx.x;
    int s = src[e], d = dst[e];
    float coef = isd[s] * isd[d];
    atomicAdd(&out[(long)d * D_FEAT + f], x[(long)s * D_FEAT + f] * coef);
}

extern "C" void kernel_launch(void* const* d_in, const int* in_sizes, int n_in,
                              void* d_out, int out_size, void* d_ws, size_t ws_size,
                              hipStream_t stream) {
    const float* x   = (const float*)d_in[0];
    const int*   src = (const int*)d_in[1];
    const int*   dst = (const int*)d_in[2];
    float* out = (float*)d_out;

    int N = in_sizes[0] / D_FEAT;   // 100000
    int E = in_sizes[1];            // 1600000

    int nslices = (N + SLICE_NODES - 1) / SLICE_NODES;   // 8 for N=100000
    int sliceSz = SLICE_NODES;

    // pick largest chunk count whose ushort scratch fits the workspace
    int nc = 64;
    size_t off_cnt, off_isd, off_misc, off_bucket, off_H, off_ovf, needed;
    for (;;) {
        size_t hSz = (size_t)2 * nslices * nc * sliceSz * 2;   // ushort
        off_cnt    = 0;
        off_isd    = off_cnt + (size_t)N * 4;
        off_misc   = off_isd + (size_t)N * 4;   // novf @+0
        off_bucket = off_misc + 64;
        off_H      = off_bucket + (size_t)N * CAP * 4;
        off_ovf    = off_H + hSz;
        needed     = off_ovf + (size_t)E * 8;
        if (ws_size >= needed || nc == 8) break;
        nc >>= 1;
    }

    if (ws_size >= needed) {
        char* ws = (char*)d_ws;
        int*            cnt    = (int*)(ws + off_cnt);
        float*          isd    = (float*)(ws + off_isd);
        int*            novf   = (int*)(ws + off_misc);
        int*            bucket = (int*)(ws + off_bucket);
        unsigned short* H      = (unsigned short*)(ws + off_H);
        int2*           ovf    = (int2*)(ws + off_ovf);

        hipMemsetAsync(novf, 0, 16, stream);

        int chunkSz = (((E + nc - 1) / nc) + 3) & ~3;   // 4-aligned

        hist_kernel<<<2 * nslices * nc, 256, 0, stream>>>(
            src, dst, H, E, N, nslices, sliceSz, chunkSz, nc);
        scan_kernel<<<(nslices * sliceSz + 255) / 256, 256, 0, stream>>>(
            H, isd, cnt, N, nslices, sliceSz, nc);
        scatter_kernel<<<nslices * nc, 256, 0, stream>>>(
            src, dst, H, bucket, ovf, novf, E, N, nslices, sliceSz, chunkSz, nc);
        gather_kernel<<<(N + NODES_PER_BLOCK - 1) / NODES_PER_BLOCK, 256, 0, stream>>>(
            (const float4*)x, cnt, bucket, isd, (float4*)out, N);
        overflow_kernel<<<64, D_FEAT, 0, stream>>>(x, isd, ovf, novf, out);
        return;
    }

    // tier-2: R3 atomic build (needs ~26.8MB)
    size_t t2_deg    = 0;
    size_t t2_cnt    = t2_deg + (size_t)N * 4;
    size_t t2_isd    = t2_cnt + (size_t)N * 4;
    size_t t2_novf   = t2_isd + (size_t)N * 4;
    size_t t2_bucket = t2_novf + 16;
    size_t t2_ovf    = t2_bucket + (size_t)N * CAP * 4;
    size_t t2_needed = t2_ovf + (size_t)E * 8;

    if (ws_size >= t2_needed) {
        char* ws = (char*)d_ws;
        int*   deg    = (int*)(ws + t2_deg);
        int*   cnt    = (int*)(ws + t2_cnt);
        float* isd    = (float*)(ws + t2_isd);
        int*   novf   = (int*)(ws + t2_novf);
        int*   bucket = (int*)(ws + t2_bucket);
        int2*  ovf    = (int2*)(ws + t2_ovf);

        hipMemsetAsync(ws, 0, t2_novf + 16, stream);
        int sl = (N + NSLICES_T2 - 1) / NSLICES_T2;
        build_kernel<<<NSLICES_T2 * BPS, 256, 0, stream>>>(src, dst, deg, cnt,
                                                           bucket, ovf, novf, E, sl);
        isd_kernel<<<(N + 255) / 256, 256, 0, stream>>>(deg, isd, N);
        gather_kernel<<<(N + NODES_PER_BLOCK - 1) / NODES_PER_BLOCK, 256, 0, stream>>>(
            (const float4*)x, cnt, bucket, isd, (float4*)out, N);
        overflow_kernel<<<64, D_FEAT, 0, stream>>>(x, isd, ovf, novf, out);
        return;
    }

    // tier-3 naive
    float* deg = (float*)d_ws;
    hipMemsetAsync(deg, 0, (size_t)N * sizeof(float), stream);
    hipMemsetAsync(out, 0, (size_t)out_size * sizeof(float), stream);
    fb_degree_kernel<<<(E + 255) / 256, 256, 0, stream>>>(src, deg, E);
    fb_inv_sqrt_kernel<<<(N + 255) / 256, 256, 0, stream>>>(deg, N);
    fb_scatter_kernel<<<E, D_FEAT, 0, stream>>>(x, src, dst, deg, out, E);
}

// Round 4
// 303.902 us; speedup vs baseline: 1.6792x; 1.0438x over previous
//
#include <hip/hip_runtime.h>

// GCNConv: out[v] = isd[v] * sum_{(u->v)} x[u] * isd[u],  isd = rsqrt(max(outdeg,1))
// N=100000, E=1600000, D=128 fp32.
//
// R1 -> R2: bucketed gather killed the 800MB atomic write storm (866 -> 367us).
// R2 -> R3: dst-range slicing for bucket-store L2 locality (367 -> 343us).
// R3 -> R4 FAILED: scope-relaxed atomics don't stay in per-XCD L2; global
//           atomic op throughput (~25G/s) is the wall regardless of scope.
// R4 -> R5: atomic-free build (LDS hist -> chunk prefix -> LDS-seeded scatter);
//           parallelism bug (128-block grids) -> 510us.
// R5 -> R6: chunk dim 16->64: 317us. gather (123us) near its L2 floor
//           (FETCH 392MB ~= 8 XCDs x unique-src-rows); build path ~194us.
// R6 -> R7: byte-packed histograms. Counts/prefixes <= max_deg (~50) fit in
//           bytes: 4 nodes/int. (1) hist: 50K-node superslice = 50KB LDS ->
//           2 slices not 8 -> edge scans 102->25.6MB; writeback = packed-int
//           copy; H scratch halves -> nc=128 fits. (2) scan: 4 nodes/thread,
//           coalesced packed ints, prefix in place. (3) scatter: s=bid%nsc
//           pins a slice to one XCD pair (write-merge in L2; slot uniqueness
//           is order-independent), packed-byte LDS seeds. Clamp 200 keeps
//           >=CAP -> ovf invariant; field overflow impossible here (deg<=~50).

#define D_FEAT 128
#define CAP 32
#define NODES_PER_BLOCK 8   // gather: 256 threads, 32 lanes (float4) per node
#define SS_NODES 50000      // hist superslice (50KB byte-packed LDS)
#define SS_INTS  12500
#define SC_NODES 25000      // scatter slice (3.2MB bucket window < 4MB L2)
#define SC_INTS   6250
#define PCLAMP   200

// ---- atomic-free build pipeline (byte-packed) ----

__global__ void hist_kernel(const int* __restrict__ src, const int* __restrict__ dst,
                            unsigned* __restrict__ H, int E, int N,
                            int nss, int chunkSz, int nc) {
    int bid = blockIdx.x;
    int ax = bid & 1;                            // 0 = src (deg), 1 = dst (cnt)
    int ss = (bid >> 1) % nss;
    int c  = bid / (2 * nss);
    const int* __restrict__ arr = ax ? dst : src;

    __shared__ unsigned hp[SS_INTS];             // 4 nodes per int, byte fields
    int lo = ss * SS_NODES;
    int span = min(N - lo, SS_NODES);
    for (int i = threadIdx.x; i < SS_INTS; i += blockDim.x) hp[i] = 0u;
    __syncthreads();

    int beg = c * chunkSz;
    int end = min(E, beg + chunkSz);
    int i = beg + (int)threadIdx.x * 4;
    for (; i + 3 < end; i += blockDim.x * 4) {
        int4 v = *reinterpret_cast<const int4*>(&arr[i]);
        unsigned o;
        o = (unsigned)(v.x - lo); if (o < (unsigned)span) atomicAdd(&hp[o >> 2], 1u << (8 * (o & 3)));
        o = (unsigned)(v.y - lo); if (o < (unsigned)span) atomicAdd(&hp[o >> 2], 1u << (8 * (o & 3)));
        o = (unsigned)(v.z - lo); if (o < (unsigned)span) atomicAdd(&hp[o >> 2], 1u << (8 * (o & 3)));
        o = (unsigned)(v.w - lo); if (o < (unsigned)span) atomicAdd(&hp[o >> 2], 1u << (8 * (o & 3)));
    }
    if (i < end) {                               // only if E%4 != 0
        for (int k = i; k < end; ++k) {
            unsigned o = (unsigned)(arr[k] - lo);
            if (o < (unsigned)span) atomicAdd(&hp[o >> 2], 1u << (8 * (o & 3)));
        }
    }
    __syncthreads();

    size_t base = ((size_t)(ax * nss + ss) * nc + c) * SS_INTS;
    for (int j = threadIdx.x; j < SS_INTS; j += blockDim.x) H[base + j] = hp[j];
}

__global__ void scan_kernel(unsigned* __restrict__ H, float* __restrict__ isd,
                            int* __restrict__ cnt, int N, int nss, int nc) {
    int g = blockIdx.x * blockDim.x + threadIdx.x;   // over nss*SS_INTS packed cols
    if (g >= nss * SS_INTS) return;
    int ss = g / SS_INTS;
    int i  = g - ss * SS_INTS;
    int node0 = ss * SS_NODES + 4 * i;

    // src axis: total out-degree -> isd (fused)
    size_t baseS = ((size_t)(0 * nss + ss) * nc) * SS_INTS + i;
    int s0 = 0, s1 = 0, s2 = 0, s3 = 0;
    for (int c = 0; c < nc; ++c) {
        unsigned w = H[baseS + (size_t)c * SS_INTS];
        s0 += w & 255; s1 += (w >> 8) & 255; s2 += (w >> 16) & 255; s3 += w >> 24;
    }
    if (node0 + 0 < N) isd[node0 + 0] = rsqrtf(fmaxf((float)s0, 1.0f));
    if (node0 + 1 < N) isd[node0 + 1] = rsqrtf(fmaxf((float)s1, 1.0f));
    if (node0 + 2 < N) isd[node0 + 2] = rsqrtf(fmaxf((float)s2, 1.0f));
    if (node0 + 3 < N) isd[node0 + 3] = rsqrtf(fmaxf((float)s3, 1.0f));

    // dst axis: exclusive per-chunk prefix, in place (thread owns these ints)
    size_t baseD = ((size_t)(1 * nss + ss) * nc) * SS_INTS + i;
    int r0 = 0, r1 = 0, r2 = 0, r3 = 0;
    for (int c = 0; c < nc; ++c) {
        size_t idx = baseD + (size_t)c * SS_INTS;
        unsigned w = H[idx];
        unsigned p = (unsigned)min(r0, PCLAMP) | ((unsigned)min(r1, PCLAMP) << 8) |
                     ((unsigned)min(r2, PCLAMP) << 16) | ((unsigned)min(r3, PCLAMP) << 24);
        H[idx] = p;
        r0 += w & 255; r1 += (w >> 8) & 255; r2 += (w >> 16) & 255; r3 += w >> 24;
    }
    if (node0 + 0 < N) cnt[node0 + 0] = r0;
    if (node0 + 1 < N) cnt[node0 + 1] = r1;
    if (node0 + 2 < N) cnt[node0 + 2] = r2;
    if (node0 + 3 < N) cnt[node0 + 3] = r3;
}

__global__ void scatter_kernel(const int* __restrict__ src, const int* __restrict__ dst,
                               const unsigned* __restrict__ H,  // dst-axis prefixes
                               int* __restrict__ bucket, int2* __restrict__ ovf,
                               int* __restrict__ novf, int E, int N,
                               int nss, int nsc, int chunkSz, int nc) {
    int bid = blockIdx.x;
    int s = bid % nsc;          // XCD-pinning heuristic: slice -> same XCD pair
    int c = bid / nsc;

    __shared__ unsigned lcp[SC_INTS];            // byte-packed running counters
    int lo = s * SC_NODES;
    int span = min(N - lo, SC_NODES);
    int ss = s >> 1;                             // SC = SS/2
    size_t base = ((size_t)(nss + ss) * nc + c) * SS_INTS + (size_t)(s & 1) * SC_INTS;
    for (int i = threadIdx.x; i < SC_INTS; i += blockDim.x) lcp[i] = H[base + i];
    __syncthreads();

    int beg = c * chunkSz;
    int end = min(E, beg + chunkSz);
    int i = beg + (int)threadIdx.x * 4;
    for (; i + 3 < end; i += blockDim.x * 4) {
        int4 dv = *reinterpret_cast<const int4*>(&dst[i]);
        int4 sv = *reinterpret_cast<const int4*>(&src[i]);
        #pragma unroll
        for (int k = 0; k < 4; ++k) {
            int d  = (&dv.x)[k];
            int sx = (&sv.x)[k];
            unsigned o = (unsigned)(d - lo);
            if (o < (unsigned)span) {
                int sh = 8 * (o & 3);
                unsigned old = atomicAdd(&lcp[o >> 2], 1u << sh);  // unique slot
                int slot = (old >> sh) & 255;
                if (slot < CAP) {
                    bucket[d * CAP + slot] = sx;                   // plain store
                } else {
                    int ov = atomicAdd(novf, 1);                   // rare tail
                    ovf[ov] = make_int2(sx, d);
                }
            }
        }
    }
    if (i < end) {                               // only if E%4 != 0
        for (int k = i; k < end; ++k) {
            int d  = dst[k];
            int sx = src[k];
            unsigned o = (unsigned)(d - lo);
            if (o < (unsigned)span) {
                int sh = 8 * (o & 3);
                unsigned old = atomicAdd(&lcp[o >> 2], 1u << sh);
                int slot = (old >> sh) & 255;
                if (slot < CAP) {
                    bucket[d * CAP + slot] = sx;
                } else {
                    int ov = atomicAdd(novf, 1);
                    ovf[ov] = make_int2(sx, d);
                }
            }
        }
    }
}

// 8 nodes per 256-thread block; 32 threads per node, float4 per thread.
__global__ void gather_kernel(const float4* __restrict__ x4,
                              const int* __restrict__ cnt,
                              const int* __restrict__ bucket,
                              const float* __restrict__ isd,
                              float4* __restrict__ out4, int N) {
    __shared__ int   sh_idx[NODES_PER_BLOCK * CAP];
    __shared__ float sh_w[NODES_PER_BLOCK * CAP];
    int t = threadIdx.x;
    int node_slot = t >> 5;
    int lane = t & 31;
    int d = blockIdx.x * NODES_PER_BLOCK + node_slot;

    int c = 0;
    if (d < N) {
        c = min(cnt[d], CAP);
        if (lane < c) {
            int s = bucket[d * CAP + lane];
            sh_idx[node_slot * CAP + lane] = s;
            sh_w[node_slot * CAP + lane] = isd[s];
        }
    }
    __syncthreads();
    if (d >= N) return;

    float4 acc = {0.f, 0.f, 0.f, 0.f};
    #pragma unroll 4
    for (int k = 0; k < c; ++k) {
        int s   = sh_idx[node_slot * CAP + k];   // broadcast LDS read
        float w = sh_w[node_slot * CAP + k];
        float4 v = x4[s * 32 + lane];            // 512B coalesced row gather
        acc.x += v.x * w; acc.y += v.y * w;
        acc.z += v.z * w; acc.w += v.w * w;
    }
    float wd = isd[d];
    acc.x *= wd; acc.y *= wd; acc.z *= wd; acc.w *= wd;
    out4[d * 32 + lane] = acc;                   // single non-atomic row write
}

__global__ void overflow_kernel(const float* __restrict__ x,
                                const float* __restrict__ isd,
                                const int2* __restrict__ ovf,
                                const int* __restrict__ novf,
                                float* __restrict__ out) {
    int n = *novf;
    for (int e = blockIdx.x; e < n; e += gridDim.x) {
        int2 sd = ovf[e];
        float coef = isd[sd.x] * isd[sd.y];
        atomicAdd(&out[sd.y * D_FEAT + threadIdx.x],
                  x[sd.x * D_FEAT + threadIdx.x] * coef);
    }
}

// ---- tier-2 (ws too small for scratch): R3 atomic build ----
#define NSLICES_T2 8
#define BPS 512

__global__ void build_kernel(const int* __restrict__ src, const int* __restrict__ dst,
                             int* __restrict__ deg, int* __restrict__ cnt,
                             int* __restrict__ bucket, int2* __restrict__ ovf,
                             int* __restrict__ novf, int E, int sliceSz) {
    int slice = blockIdx.x & (NSLICES_T2 - 1);
    int chunk = blockIdx.x >> 3;
    int lo = slice * sliceSz;
    int hi = lo + sliceSz;
    int chunkSz = (E + BPS - 1) / BPS;
    int beg = chunk * chunkSz;
    int end = min(E, beg + chunkSz);

    for (int i = beg + (int)threadIdx.x; i < end; i += blockDim.x) {
        int s = src[i];
        int d = dst[i];
        if (d >= lo && d < hi) {
            int slot = atomicAdd(&cnt[d], 1);
            if (slot < CAP) {
                bucket[d * CAP + slot] = s;
            } else {
                int o = atomicAdd(novf, 1);
                ovf[o] = make_int2(s, d);
            }
        }
        if (s >= lo && s < hi) {
            atomicAdd(&deg[s], 1);
        }
    }
}

__global__ void isd_kernel(const int* __restrict__ deg, float* __restrict__ isd, int N) {
    int i = blockIdx.x * blockDim.x + threadIdx.x;
    if (i < N) isd[i] = rsqrtf(fmaxf((float)deg[i], 1.0f));
}

// ---- tier-3 fallback (ws tiny): round-1 atomic scatter ----
__global__ void fb_degree_kernel(const int* __restrict__ src,
                                 float* __restrict__ deg, int E) {
    int i = blockIdx.x * blockDim.x + threadIdx.x;
    if (i < E) atomicAdd(&deg[src[i]], 1.0f);
}
__global__ void fb_inv_sqrt_kernel(float* __restrict__ deg, int N) {
    int i = blockIdx.x * blockDim.x + threadIdx.x;
    if (i < N) deg[i] = rsqrtf(fmaxf(deg[i], 1.0f));
}
__global__ void fb_scatter_kernel(const float* __restrict__ x,
                                  const int* __restrict__ src,
                                  const int* __restrict__ dst,
                                  const float* __restrict__ isd,
                                  float* __restrict__ out, int E) {
    int e = blockIdx.x;
    if (e >= E) return;
    int f = threadIdx.x;
    int s = src[e], d = dst[e];
    float coef = isd[s] * isd[d];
    atomicAdd(&out[(long)d * D_FEAT + f], x[(long)s * D_FEAT + f] * coef);
}

extern "C" void kernel_launch(void* const* d_in, const int* in_sizes, int n_in,
                              void* d_out, int out_size, void* d_ws, size_t ws_size,
                              hipStream_t stream) {
    const float* x   = (const float*)d_in[0];
    const int*   src = (const int*)d_in[1];
    const int*   dst = (const int*)d_in[2];
    float* out = (float*)d_out;

    int N = in_sizes[0] / D_FEAT;   // 100000
    int E = in_sizes[1];            // 1600000

    int nss = (N + SS_NODES - 1) / SS_NODES;    // 2
    int nsc = (N + SC_NODES - 1) / SC_NODES;    // 4

    // pick largest chunk count whose byte scratch fits the workspace
    int nc = 128;
    size_t off_cnt, off_isd, off_misc, off_bucket, off_H, off_ovf, needed;
    for (;;) {
        size_t hSz = (size_t)2 * nss * nc * SS_INTS * 4;   // packed bytes
        off_cnt    = 0;
        off_isd    = off_cnt + (size_t)N * 4;
        off_misc   = off_isd + (size_t)N * 4;   // novf @+0
        off_bucket = off_misc + 64;
        off_H      = off_bucket + (size_t)N * CAP * 4;
        off_ovf    = off_H + hSz;
        needed     = off_ovf + (size_t)E * 8;
        if (ws_size >= needed || nc == 16) break;
        nc >>= 1;
    }

    if (ws_size >= needed) {
        char* ws = (char*)d_ws;
        int*      cnt    = (int*)(ws + off_cnt);
        float*    isd    = (float*)(ws + off_isd);
        int*      novf   = (int*)(ws + off_misc);
        int*      bucket = (int*)(ws + off_bucket);
        unsigned* H      = (unsigned*)(ws + off_H);
        int2*     ovf    = (int2*)(ws + off_ovf);

        hipMemsetAsync(novf, 0, 16, stream);

        int chunkSz = (((E + nc - 1) / nc) + 3) & ~3;   // 4-aligned

        hist_kernel<<<2 * nss * nc, 256, 0, stream>>>(
            src, dst, H, E, N, nss, chunkSz, nc);
        scan_kernel<<<(nss * SS_INTS + 255) / 256, 256, 0, stream>>>(
            H, isd, cnt, N, nss, nc);
        scatter_kernel<<<nsc * nc, 256, 0, stream>>>(
            src, dst, H, bucket, ovf, novf, E, N, nss, nsc, chunkSz, nc);
        gather_kernel<<<(N + NODES_PER_BLOCK - 1) / NODES_PER_BLOCK, 256, 0, stream>>>(
            (const float4*)x, cnt, bucket, isd, (float4*)out, N);
        overflow_kernel<<<64, D_FEAT, 0, stream>>>(x, isd, ovf, novf, out);
        return;
    }

    // tier-2: R3 atomic build (needs ~26.8MB)
    size_t t2_deg    = 0;
    size_t t2_cnt    = t2_deg + (size_t)N * 4;
    size_t t2_isd    = t2_cnt + (size_t)N * 4;
    size_t t2_novf   = t2_isd + (size_t)N * 4;
    size_t t2_bucket = t2_novf + 16;
    size_t t2_ovf    = t2_bucket + (size_t)N * CAP * 4;
    size_t t2_needed = t2_ovf + (size_t)E * 8;

    if (ws_size >= t2_needed) {
        char* ws = (char*)d_ws;
        int*   deg    = (int*)(ws + t2_deg);
        int*   cnt    = (int*)(ws + t2_cnt);
        float* isd    = (float*)(ws + t2_isd);
        int*   novf   = (int*)(ws + t2_novf);
        int*   bucket = (int*)(ws + t2_bucket);
        int2*  ovf    = (int2*)(ws + t2_ovf);

        hipMemsetAsync(ws, 0, t2_novf + 16, stream);
        int sl = (N + NSLICES_T2 - 1) / NSLICES_T2;
        build_kernel<<<NSLICES_T2 * BPS, 256, 0, stream>>>(src, dst, deg, cnt,
                                                           bucket, ovf, novf, E, sl);
        isd_kernel<<<(N + 255) / 256, 256, 0, stream>>>(deg, isd, N);
        gather_kernel<<<(N + NODES_PER_BLOCK - 1) / NODES_PER_BLOCK, 256, 0, stream>>>(
            (const float4*)x, cnt, bucket, isd, (float4*)out, N);
        overflow_kernel<<<64, D_FEAT, 0, stream>>>(x, isd, ovf, novf, out);
        return;
    }

    // tier-3 naive
    float* deg = (float*)d_ws;
    hipMemsetAsync(deg, 0, (size_t)N * sizeof(float), stream);
    hipMemsetAsync(out, 0, (size_t)out_size * sizeof(float), stream);
    fb_degree_kernel<<<(E + 255) / 256, 256, 0, stream>>>(src, deg, E);
    fb_inv_sqrt_kernel<<<(N + 255) / 256, 256, 0, stream>>>(deg, N);
    fb_scatter_kernel<<<E, D_FEAT, 0, stream>>>(x, src, dst, deg, out, E);
}

// Round 5
// 253.079 us; speedup vs baseline: 2.0164x; 1.2008x over previous
//
#include <hip/hip_runtime.h>
#include <hip/hip_fp16.h>

// GCNConv: out[v] = isd[v] * sum_{(u->v)} x[u] * isd[u],  isd = rsqrt(max(outdeg,1))
// N=100000, E=1600000, D=128 fp32.
//
// R1 -> R2: bucketed gather killed the 800MB atomic write storm (866 -> 367us).
// R2 -> R3: dst-range slicing for bucket-store L2 locality (367 -> 343us).
// R3 -> R4 FAILED: scope-relaxed atomics don't escape the coherence point;
//           global atomic throughput (~25G/s) is the wall regardless of scope.
// R4 -> R5: atomic-free build (LDS hist -> chunk prefix -> LDS-seeded scatter);
//           parallelism bug (128-block grids) -> 510us.
// R5 -> R6: chunk dim 16->64: 317us.
// R6 -> R7: byte-packed hist (4 nodes/int): 304us. gather stable at 123us
//           (FETCH 392MB = 8 XCDs x full 49MB x: compulsory L2 misses).
// R7 -> R8: (a) scan was latency-serial (196 blocks, 256 strided LLC-miss
//           loads/thread, no unroll) -> split axes across threads + manual
//           8x unroll: 8 loads in flight. (b) fp16 gather: convert x->half
//           AFTER scatter into a buffer UNIONED with H (both 25.6MB, zero
//           extra ws); per-XCD compulsory traffic halves (392->~200MB).
//           fp16 err ~5e-4 << 3.9e-3 tolerance.

#define D_FEAT 128
#define CAP 32
#define NODES_PER_BLOCK 8   // gather: 256 threads, 32 lanes per node
#define SS_NODES 50000      // hist superslice (50KB byte-packed LDS)
#define SS_INTS  12500
#define SC_NODES 25000      // scatter slice (3.2MB bucket window < 4MB L2)
#define SC_INTS   6250
#define PCLAMP   200

// ---- atomic-free build pipeline (byte-packed) ----

__global__ void hist_kernel(const int* __restrict__ src, const int* __restrict__ dst,
                            unsigned* __restrict__ H, int E, int N,
                            int nss, int chunkSz, int nc) {
    int bid = blockIdx.x;
    int ax = bid & 1;                            // 0 = src (deg), 1 = dst (cnt)
    int ss = (bid >> 1) % nss;
    int c  = bid / (2 * nss);
    const int* __restrict__ arr = ax ? dst : src;

    __shared__ unsigned hp[SS_INTS];             // 4 nodes per int, byte fields
    int lo = ss * SS_NODES;
    int span = min(N - lo, SS_NODES);
    for (int i = threadIdx.x; i < SS_INTS; i += blockDim.x) hp[i] = 0u;
    __syncthreads();

    int beg = c * chunkSz;
    int end = min(E, beg + chunkSz);
    int i = beg + (int)threadIdx.x * 4;
    for (; i + 3 < end; i += blockDim.x * 4) {
        int4 v = *reinterpret_cast<const int4*>(&arr[i]);
        unsigned o;
        o = (unsigned)(v.x - lo); if (o < (unsigned)span) atomicAdd(&hp[o >> 2], 1u << (8 * (o & 3)));
        o = (unsigned)(v.y - lo); if (o < (unsigned)span) atomicAdd(&hp[o >> 2], 1u << (8 * (o & 3)));
        o = (unsigned)(v.z - lo); if (o < (unsigned)span) atomicAdd(&hp[o >> 2], 1u << (8 * (o & 3)));
        o = (unsigned)(v.w - lo); if (o < (unsigned)span) atomicAdd(&hp[o >> 2], 1u << (8 * (o & 3)));
    }
    if (i < end) {                               // only if E%4 != 0
        for (int k = i; k < end; ++k) {
            unsigned o = (unsigned)(arr[k] - lo);
            if (o < (unsigned)span) atomicAdd(&hp[o >> 2], 1u << (8 * (o & 3)));
        }
    }
    __syncthreads();

    size_t base = ((size_t)(ax * nss + ss) * nc + c) * SS_INTS;
    for (int j = threadIdx.x; j < SS_INTS; j += blockDim.x) H[base + j] = hp[j];
}

// One thread per (axis, packed-col). 8x unrolled chunk walk: 8 loads in flight.
__global__ void scan_kernel(unsigned* __restrict__ H, float* __restrict__ isd,
                            int* __restrict__ cnt, int N, int nss, int nc) {
    int total = nss * SS_INTS;
    int g = blockIdx.x * blockDim.x + threadIdx.x;
    if (g >= 2 * total) return;
    int ax = (g >= total) ? 1 : 0;
    int gg = g - ax * total;
    int ss = gg / SS_INTS;
    int i  = gg - ss * SS_INTS;
    int node0 = ss * SS_NODES + 4 * i;

    size_t base = ((size_t)(ax * nss + ss) * nc) * SS_INTS + i;

    if (ax == 0) {
        // src axis: total out-degree -> isd (fused)
        int s0 = 0, s1 = 0, s2 = 0, s3 = 0;
        for (int c = 0; c < nc; c += 8) {
            unsigned w[8];
            #pragma unroll
            for (int u = 0; u < 8; ++u) w[u] = H[base + (size_t)(c + u) * SS_INTS];
            #pragma unroll
            for (int u = 0; u < 8; ++u) {
                s0 += w[u] & 255; s1 += (w[u] >> 8) & 255;
                s2 += (w[u] >> 16) & 255; s3 += w[u] >> 24;
            }
        }
        if (node0 + 0 < N) isd[node0 + 0] = rsqrtf(fmaxf((float)s0, 1.0f));
        if (node0 + 1 < N) isd[node0 + 1] = rsqrtf(fmaxf((float)s1, 1.0f));
        if (node0 + 2 < N) isd[node0 + 2] = rsqrtf(fmaxf((float)s2, 1.0f));
        if (node0 + 3 < N) isd[node0 + 3] = rsqrtf(fmaxf((float)s3, 1.0f));
    } else {
        // dst axis: exclusive per-chunk prefix, in place
        int r0 = 0, r1 = 0, r2 = 0, r3 = 0;
        for (int c = 0; c < nc; c += 8) {
            unsigned w[8];
            #pragma unroll
            for (int u = 0; u < 8; ++u) w[u] = H[base + (size_t)(c + u) * SS_INTS];
            #pragma unroll
            for (int u = 0; u < 8; ++u) {
                unsigned p = (unsigned)min(r0, PCLAMP) | ((unsigned)min(r1, PCLAMP) << 8) |
                             ((unsigned)min(r2, PCLAMP) << 16) | ((unsigned)min(r3, PCLAMP) << 24);
                H[base + (size_t)(c + u) * SS_INTS] = p;
                r0 += w[u] & 255; r1 += (w[u] >> 8) & 255;
                r2 += (w[u] >> 16) & 255; r3 += w[u] >> 24;
            }
        }
        if (node0 + 0 < N) cnt[node0 + 0] = r0;
        if (node0 + 1 < N) cnt[node0 + 1] = r1;
        if (node0 + 2 < N) cnt[node0 + 2] = r2;
        if (node0 + 3 < N) cnt[node0 + 3] = r3;
    }
}

__global__ void scatter_kernel(const int* __restrict__ src, const int* __restrict__ dst,
                               const unsigned* __restrict__ H,  // dst-axis prefixes
                               int* __restrict__ bucket, int2* __restrict__ ovf,
                               int* __restrict__ novf, int E, int N,
                               int nss, int nsc, int chunkSz, int nc) {
    int bid = blockIdx.x;
    int s = bid % nsc;          // XCD-pinning heuristic: slice -> same XCD pair
    int c = bid / nsc;

    __shared__ unsigned lcp[SC_INTS];            // byte-packed running counters
    int lo = s * SC_NODES;
    int span = min(N - lo, SC_NODES);
    int ss = s >> 1;                             // SC = SS/2
    size_t base = ((size_t)(nss + ss) * nc + c) * SS_INTS + (size_t)(s & 1) * SC_INTS;
    for (int i = threadIdx.x; i < SC_INTS; i += blockDim.x) lcp[i] = H[base + i];
    __syncthreads();

    int beg = c * chunkSz;
    int end = min(E, beg + chunkSz);
    int i = beg + (int)threadIdx.x * 4;
    for (; i + 3 < end; i += blockDim.x * 4) {
        int4 dv = *reinterpret_cast<const int4*>(&dst[i]);
        int4 sv = *reinterpret_cast<const int4*>(&src[i]);
        #pragma unroll
        for (int k = 0; k < 4; ++k) {
            int d  = (&dv.x)[k];
            int sx = (&sv.x)[k];
            unsigned o = (unsigned)(d - lo);
            if (o < (unsigned)span) {
                int sh = 8 * (o & 3);
                unsigned old = atomicAdd(&lcp[o >> 2], 1u << sh);  // unique slot
                int slot = (old >> sh) & 255;
                if (slot < CAP) {
                    bucket[d * CAP + slot] = sx;                   // plain store
                } else {
                    int ov = atomicAdd(novf, 1);                   // rare tail
                    ovf[ov] = make_int2(sx, d);
                }
            }
        }
    }
    if (i < end) {                               // only if E%4 != 0
        for (int k = i; k < end; ++k) {
            int d  = dst[k];
            int sx = src[k];
            unsigned o = (unsigned)(d - lo);
            if (o < (unsigned)span) {
                int sh = 8 * (o & 3);
                unsigned old = atomicAdd(&lcp[o >> 2], 1u << sh);
                int slot = (old >> sh) & 255;
                if (slot < CAP) {
                    bucket[d * CAP + slot] = sx;
                } else {
                    int ov = atomicAdd(novf, 1);
                    ovf[ov] = make_int2(sx, d);
                }
            }
        }
    }
}

// x fp32 -> fp16 (runs after scatter; x16 unions with H scratch)
__global__ void cvt_kernel(const float4* __restrict__ x4,
                           ushort4* __restrict__ x16, int n4) {
    int i = blockIdx.x * blockDim.x + threadIdx.x;
    if (i < n4) {
        float4 v = x4[i];
        ushort4 h;
        h.x = __half_as_ushort(__float2half_rn(v.x));
        h.y = __half_as_ushort(__float2half_rn(v.y));
        h.z = __half_as_ushort(__float2half_rn(v.z));
        h.w = __half_as_ushort(__float2half_rn(v.w));
        x16[i] = h;
    }
}

// 8 nodes per 256-thread block; 32 threads per node, 4 halves (8B) per thread.
__global__ void gather_kernel(const ushort4* __restrict__ x16,
                              const int* __restrict__ cnt,
                              const int* __restrict__ bucket,
                              const float* __restrict__ isd,
                              float4* __restrict__ out4, int N) {
    __shared__ int   sh_idx[NODES_PER_BLOCK * CAP];
    __shared__ float sh_w[NODES_PER_BLOCK * CAP];
    int t = threadIdx.x;
    int node_slot = t >> 5;
    int lane = t & 31;
    int d = blockIdx.x * NODES_PER_BLOCK + node_slot;

    int c = 0;
    if (d < N) {
        c = min(cnt[d], CAP);
        if (lane < c) {
            int s = bucket[d * CAP + lane];
            sh_idx[node_slot * CAP + lane] = s;
            sh_w[node_slot * CAP + lane] = isd[s];
        }
    }
    __syncthreads();
    if (d >= N) return;

    float4 acc = {0.f, 0.f, 0.f, 0.f};
    #pragma unroll 4
    for (int k = 0; k < c; ++k) {
        int s   = sh_idx[node_slot * CAP + k];   // broadcast LDS read
        float w = sh_w[node_slot * CAP + k];
        ushort4 v = x16[s * 32 + lane];          // 256B coalesced half-row gather
        acc.x += __half2float(__ushort_as_half(v.x)) * w;
        acc.y += __half2float(__ushort_as_half(v.y)) * w;
        acc.z += __half2float(__ushort_as_half(v.z)) * w;
        acc.w += __half2float(__ushort_as_half(v.w)) * w;
    }
    float wd = isd[d];
    acc.x *= wd; acc.y *= wd; acc.z *= wd; acc.w *= wd;
    out4[d * 32 + lane] = acc;                   // single non-atomic row write
}

__global__ void overflow_kernel(const float* __restrict__ x,
                                const float* __restrict__ isd,
                                const int2* __restrict__ ovf,
                                const int* __restrict__ novf,
                                float* __restrict__ out) {
    int n = *novf;
    for (int e = blockIdx.x; e < n; e += gridDim.x) {
        int2 sd = ovf[e];
        float coef = isd[sd.x] * isd[sd.y];
        atomicAdd(&out[sd.y * D_FEAT + threadIdx.x],
                  x[sd.x * D_FEAT + threadIdx.x] * coef);
    }
}

// fp32 gather for tier-2 (no x16 buffer available)
__global__ void gather32_kernel(const float4* __restrict__ x4,
                                const int* __restrict__ cnt,
                                const int* __restrict__ bucket,
                                const float* __restrict__ isd,
                                float4* __restrict__ out4, int N) {
    __shared__ int   sh_idx[NODES_PER_BLOCK * CAP];
    __shared__ float sh_w[NODES_PER_BLOCK * CAP];
    int t = threadIdx.x;
    int node_slot = t >> 5;
    int lane = t & 31;
    int d = blockIdx.x * NODES_PER_BLOCK + node_slot;

    int c = 0;
    if (d < N) {
        c = min(cnt[d], CAP);
        if (lane < c) {
            int s = bucket[d * CAP + lane];
            sh_idx[node_slot * CAP + lane] = s;
            sh_w[node_slot * CAP + lane] = isd[s];
        }
    }
    __syncthreads();
    if (d >= N) return;

    float4 acc = {0.f, 0.f, 0.f, 0.f};
    #pragma unroll 4
    for (int k = 0; k < c; ++k) {
        int s   = sh_idx[node_slot * CAP + k];
        float w = sh_w[node_slot * CAP + k];
        float4 v = x4[s * 32 + lane];
        acc.x += v.x * w; acc.y += v.y * w;
        acc.z += v.z * w; acc.w += v.w * w;
    }
    float wd = isd[d];
    acc.x *= wd; acc.y *= wd; acc.z *= wd; acc.w *= wd;
    out4[d * 32 + lane] = acc;
}

// ---- tier-2 (ws too small for scratch): atomic build ----
#define NSLICES_T2 8
#define BPS 512

__global__ void build_kernel(const int* __restrict__ src, const int* __restrict__ dst,
                             int* __restrict__ deg, int* __restrict__ cnt,
                             int* __restrict__ bucket, int2* __restrict__ ovf,
                             int* __restrict__ novf, int E, int sliceSz) {
    int slice = blockIdx.x & (NSLICES_T2 - 1);
    int chunk = blockIdx.x >> 3;
    int lo = slice * sliceSz;
    int hi = lo + sliceSz;
    int chunkSz = (E + BPS - 1) / BPS;
    int beg = chunk * chunkSz;
    int end = min(E, beg + chunkSz);

    for (int i = beg + (int)threadIdx.x; i < end; i += blockDim.x) {
        int s = src[i];
        int d = dst[i];
        if (d >= lo && d < hi) {
            int slot = atomicAdd(&cnt[d], 1);
            if (slot < CAP) {
                bucket[d * CAP + slot] = s;
            } else {
                int o = atomicAdd(novf, 1);
                ovf[o] = make_int2(s, d);
            }
        }
        if (s >= lo && s < hi) {
            atomicAdd(&deg[s], 1);
        }
    }
}

__global__ void isd_kernel(const int* __restrict__ deg, float* __restrict__ isd, int N) {
    int i = blockIdx.x * blockDim.x + threadIdx.x;
    if (i < N) isd[i] = rsqrtf(fmaxf((float)deg[i], 1.0f));
}

// ---- tier-3 fallback (ws tiny): round-1 atomic scatter ----
__global__ void fb_degree_kernel(const int* __restrict__ src,
                                 float* __restrict__ deg, int E) {
    int i = blockIdx.x * blockDim.x + threadIdx.x;
    if (i < E) atomicAdd(&deg[src[i]], 1.0f);
}
__global__ void fb_inv_sqrt_kernel(float* __restrict__ deg, int N) {
    int i = blockIdx.x * blockDim.x + threadIdx.x;
    if (i < N) deg[i] = rsqrtf(fmaxf(deg[i], 1.0f));
}
__global__ void fb_scatter_kernel(const float* __restrict__ x,
                                  const int* __restrict__ src,
                                  const int* __restrict__ dst,
                                  const float* __restrict__ isd,
                                  float* __restrict__ out, int E) {
    int e = blockIdx.x;
    if (e >= E) return;
    int f = threadIdx.x;
    int s = src[e], d = dst[e];
    float coef = isd[s] * isd[d];
    atomicAdd(&out[(long)d * D_FEAT + f], x[(long)s * D_FEAT + f] * coef);
}

extern "C" void kernel_launch(void* const* d_in, const int* in_sizes, int n_in,
                              void* d_out, int out_size, void* d_ws, size_t ws_size,
                              hipStream_t stream) {
    const float* x   = (const float*)d_in[0];
    const int*   src = (const int*)d_in[1];
    const int*   dst = (const int*)d_in[2];
    float* out = (float*)d_out;

    int N = in_sizes[0] / D_FEAT;   // 100000
    int E = in_sizes[1];            // 1600000

    int nss = (N + SS_NODES - 1) / SS_NODES;    // 2
    int nsc = (N + SC_NODES - 1) / SC_NODES;    // 4

    size_t x16Sz = (size_t)N * D_FEAT * 2;      // 25.6 MB fp16 copy of x

    // pick largest chunk count whose scratch fits (H unions with x16)
    int nc = 128;
    size_t off_cnt, off_isd, off_misc, off_bucket, off_H, off_ovf, needed;
    for (;;) {
        size_t hSz = (size_t)2 * nss * nc * SS_INTS * 4;   // packed bytes
        size_t uSz = hSz > x16Sz ? hSz : x16Sz;            // union(H, x16)
        off_cnt    = 0;
        off_isd    = off_cnt + (size_t)N * 4;
        off_misc   = off_isd + (size_t)N * 4;   // novf @+0
        off_bucket = off_misc + 64;
        off_H      = off_bucket + (size_t)N * CAP * 4;
        off_ovf    = off_H + uSz;
        needed     = off_ovf + (size_t)E * 8;
        if (ws_size >= needed || nc == 16) break;
        nc >>= 1;
    }

    if (ws_size >= needed) {
        char* ws = (char*)d_ws;
        int*      cnt    = (int*)(ws + off_cnt);
        float*    isd    = (float*)(ws + off_isd);
        int*      novf   = (int*)(ws + off_misc);
        int*      bucket = (int*)(ws + off_bucket);
        unsigned* H      = (unsigned*)(ws + off_H);
        ushort4*  x16    = (ushort4*)(ws + off_H);   // union: valid after scatter
        int2*     ovf    = (int2*)(ws + off_ovf);

        hipMemsetAsync(novf, 0, 16, stream);

        int chunkSz = (((E + nc - 1) / nc) + 3) & ~3;   // 4-aligned

        hist_kernel<<<2 * nss * nc, 256, 0, stream>>>(
            src, dst, H, E, N, nss, chunkSz, nc);
        scan_kernel<<<(2 * nss * SS_INTS + 255) / 256, 256, 0, stream>>>(
            H, isd, cnt, N, nss, nc);
        scatter_kernel<<<nsc * nc, 256, 0, stream>>>(
            src, dst, H, bucket, ovf, novf, E, N, nss, nsc, chunkSz, nc);
        int n4 = N * (D_FEAT / 4);
        cvt_kernel<<<(n4 + 255) / 256, 256, 0, stream>>>(
            (const float4*)x, x16, n4);
        gather_kernel<<<(N + NODES_PER_BLOCK - 1) / NODES_PER_BLOCK, 256, 0, stream>>>(
            x16, cnt, bucket, isd, (float4*)out, N);
        overflow_kernel<<<64, D_FEAT, 0, stream>>>(x, isd, ovf, novf, out);
        return;
    }

    // tier-2: atomic build (needs ~26.8MB)
    size_t t2_deg    = 0;
    size_t t2_cnt    = t2_deg + (size_t)N * 4;
    size_t t2_isd    = t2_cnt + (size_t)N * 4;
    size_t t2_novf   = t2_isd + (size_t)N * 4;
    size_t t2_bucket = t2_novf + 16;
    size_t t2_ovf    = t2_bucket + (size_t)N * CAP * 4;
    size_t t2_needed = t2_ovf + (size_t)E * 8;

    if (ws_size >= t2_needed) {
        char* ws = (char*)d_ws;
        int*   deg    = (int*)(ws + t2_deg);
        int*   cnt    = (int*)(ws + t2_cnt);
        float* isd    = (float*)(ws + t2_isd);
        int*   novf   = (int*)(ws + t2_novf);
        int*   bucket = (int*)(ws + t2_bucket);
        int2*  ovf    = (int2*)(ws + t2_ovf);

        hipMemsetAsync(ws, 0, t2_novf + 16, stream);
        int sl = (N + NSLICES_T2 - 1) / NSLICES_T2;
        build_kernel<<<NSLICES_T2 * BPS, 256, 0, stream>>>(src, dst, deg, cnt,
                                                           bucket, ovf, novf, E, sl);
        isd_kernel<<<(N + 255) / 256, 256, 0, stream>>>(deg, isd, N);
        gather32_kernel<<<(N + NODES_PER_BLOCK - 1) / NODES_PER_BLOCK, 256, 0, stream>>>(
            (const float4*)x, cnt, bucket, isd, (float4*)out, N);
        overflow_kernel<<<64, D_FEAT, 0, stream>>>(x, isd, ovf, novf, out);
        return;
    }

    // tier-3 naive
    float* deg = (float*)d_ws;
    hipMemsetAsync(deg, 0, (size_t)N * sizeof(float), stream);
    hipMemsetAsync(out, 0, (size_t)out_size * sizeof(float), stream);
    fb_degree_kernel<<<(E + 255) / 256, 256, 0, stream>>>(src, deg, E);
    fb_inv_sqrt_kernel<<<(N + 255) / 256, 256, 0, stream>>>(deg, N);
    fb_scatter_kernel<<<E, D_FEAT, 0, stream>>>(x, src, dst, deg, out, E);
}